// Round 6
// baseline (171.143 us; speedup 1.0000x reference)
//
#include <hip/hip_runtime.h>
#include <math.h>

#define BB 32
#define FF 256
#define N1 64
#define N2 256

typedef _Float16 f16;
typedef _Float16 f16x4 __attribute__((ext_vector_type(4)));
typedef _Float16 f16x8 __attribute__((ext_vector_type(8)));
typedef float f32x4 __attribute__((ext_vector_type(4)));

// ---- ws byte offsets ----
#define OFFB_W14T 0u        // 4*256 f32  (W1 cols 0..3, [c][o])
#define OFFB_INVT 4096u     // 32*64 f32
#define OFFB_INVS 12288u    // 32*256 f32
#define OFFB_W1H  45056u    // 256*256 f16 (W1 cols 4..259, [o][k])
#define OFFB_W2H  176128u
#define OFFB_W3H  307200u
#define OFFB_W4H  438272u
#define OFFB_W5H  569344u

__global__ void k_prep(const float* __restrict__ W1, const float* __restrict__ W2,
                       const float* __restrict__ W3, const float* __restrict__ W4,
                       const float* __restrict__ W5, char* __restrict__ wsb) {
  int x = blockIdx.x, m = blockIdx.y, t = threadIdx.x;
  int idx = x * 256 + t;
  if (m == 0)      ((f16*)(wsb + OFFB_W2H))[idx] = (f16)W2[idx];
  else if (m == 1) ((f16*)(wsb + OFFB_W3H))[idx] = (f16)W3[idx];
  else if (m == 2) ((f16*)(wsb + OFFB_W4H))[idx] = (f16)W4[idx];
  else if (m == 3) ((f16*)(wsb + OFFB_W5H))[idx] = (f16)W5[idx];
  else if (m == 4) ((f16*)(wsb + OFFB_W1H))[idx] = (f16)W1[x * 260 + 4 + t];
  else if (x < 4)  ((float*)(wsb + OFFB_W14T))[x * 256 + t] = W1[t * 260 + x];
}

__global__ void k_norms(const float* __restrict__ s, const float* __restrict__ t,
                        char* __restrict__ wsb) {
  int b = blockIdx.x, tid = threadIdx.x;
  float* invt = (float*)(wsb + OFFB_INVT);
  float* invs = (float*)(wsb + OFFB_INVS);
  {
    const float* sp = s + b * FF * N2 + tid;
    float acc = 0.f;
#pragma unroll 4
    for (int f = 0; f < FF; ++f) { float v = sp[f * N2]; acc = fmaf(v, v, acc); }
    invs[b * N2 + tid] = 1.0f / fmaxf(sqrtf(acc), 1e-8f);
  }
  if (tid < N1) {
    const float* tp = t + b * FF * N1 + tid;
    float acc = 0.f;
#pragma unroll 4
    for (int f = 0; f < FF; ++f) { float v = tp[f * N1]; acc = fmaf(v, v, acc); }
    invt[b * N1 + tid] = 1.0f / fmaxf(sqrtf(acc), 1e-8f);
  }
}

// Fragment-ordered layouts (verified R3/R4):
// 32m x 256k tile: frag(ks,mf) at (ks*2+mf)*1024, lane L at +L*16 (b128, no-conflict)
// 64n x 256f t-tile: frag((f>>5)*4 + (n>>4))*1024.

#define ZERO_ACC                                                  \
  _Pragma("unroll") for (int of = 0; of < 2; ++of)                \
  _Pragma("unroll") for (int mf = 0; mf < 2; ++mf)                \
      acc[of][mf] = (f32x4){0.f, 0.f, 0.f, 0.f};

// Software-pipelined GEMM: load B-frags one ks ahead of the MFMAs using them.
#define GEMM2(SRC)                                                                \
  {                                                                               \
    f16x8 bfa0 = *(const f16x8*)((SRC) + 0 * 1024 + lane * 16);                   \
    f16x8 bfa1 = *(const f16x8*)((SRC) + 1 * 1024 + lane * 16);                   \
    __builtin_amdgcn_s_setprio(1);                                                \
    _Pragma("unroll") for (int ks = 0; ks < 8; ++ks) {                            \
      f16x8 bfb0 = bfa0, bfb1 = bfa1;                                             \
      if (ks < 7) {                                                               \
        bfb0 = *(const f16x8*)((SRC) + ((ks + 1) * 2 + 0) * 1024 + lane * 16);    \
        bfb1 = *(const f16x8*)((SRC) + ((ks + 1) * 2 + 1) * 1024 + lane * 16);    \
      }                                                                           \
      _Pragma("unroll") for (int of = 0; of < 2; ++of) {                          \
        acc[of][0] = __builtin_amdgcn_mfma_f32_16x16x32_f16(wreg[of][ks], bfa0,   \
                                                            acc[of][0], 0, 0, 0); \
        acc[of][1] = __builtin_amdgcn_mfma_f32_16x16x32_f16(wreg[of][ks], bfa1,   \
                                                            acc[of][1], 0, 0, 0); \
      }                                                                           \
      bfa0 = bfb0; bfa1 = bfb1;                                                   \
    }                                                                             \
    __builtin_amdgcn_s_setprio(0);                                                \
  }

// bias+relu+cvt, store acc frags into 32m x 256k tile (k-dim = this layer's o)
#define STORE_FRAG(DST)                                                           \
  _Pragma("unroll") for (int of = 0; of < 2; ++of)                                \
  _Pragma("unroll") for (int mf = 0; mf < 2; ++mf) {                              \
    f16x4 hv;                                                                     \
    _Pragma("unroll") for (int j = 0; j < 4; ++j)                                 \
        hv[j] = (f16)fmaxf(acc[of][mf][j] + biasv[of][j], 0.f);                   \
    *(f16x4*)((DST) + (wg * 2 + mf) * 1024 + (of * 2 + (g >> 1)) * 256 +          \
              r * 16 + (g & 1) * 8) = hv;                                         \
  }

#define POOLUP                                                                    \
  _Pragma("unroll") for (int of = 0; of < 2; ++of)                                \
  _Pragma("unroll") for (int mf = 0; mf < 2; ++mf)                                \
  _Pragma("unroll") for (int j = 0; j < 4; ++j) {                                 \
    f16 hv = (f16)fmaxf(acc[of][mf][j] + biasv[of][j], 0.f);                      \
    if (hv > pool[of][mf][j]) pool[of][mf][j] = hv;                               \
  }

// wave w produces y1 frag (ks=w>>1, mf=w&1) for row NN
#define PRODUCE_Y1(NN, DST)                                                       \
  {                                                                               \
    float simv = sml[(NN) * 32 + mp * 16 + r];                                    \
    f16x8 c8 = *(const f16x8*)(c1h + (NN) * 264 + kp * 32 + g * 8);               \
    f16x8 h;                                                                      \
    _Pragma("unroll") for (int q = 0; q < 4; ++q) {                               \
      h[q] = (f16)fmaxf(fmaf(w1a[q], simv, (float)c8[q]), 0.f);                   \
      h[4 + q] = (f16)fmaxf(fmaf(w1b[q], simv, (float)c8[4 + q]), 0.f);           \
    }                                                                             \
    *(f16x8*)((DST) + w * 1024 + lane * 16) = h;                                  \
  }

// 16 waves: A=0-7 (L2/L4), B=8-15 (L3+pool/L5). o-split 32/wave -> wreg 64 VGPR.
// Phase skew: B produces y1[n+1] BEFORE its GEMM; A after. De-lockstep groups.
__global__ __launch_bounds__(1024, 4) void k_mega(
    const float* __restrict__ sf, const float* __restrict__ tf,
    const float* __restrict__ seeds, const float* __restrict__ b1,
    const float* __restrict__ b2, const float* __restrict__ b3,
    const float* __restrict__ b4, const float* __restrict__ b5,
    const char* __restrict__ wsb, float* __restrict__ out) {
  const int mt = blockIdx.x, b = blockIdx.y, mb = mt * 32;
  const int tid = threadIdx.x;
  const int w = tid >> 6, lane = tid & 63, g = lane >> 4, r = lane & 15;
  const int grp = w >> 3, wg = w & 7;
  const int kp = w >> 1, mp = w & 1;

  const float* w14t = (const float*)(wsb + OFFB_W14T);
  const float* invt = (const float*)(wsb + OFFB_INVT) + b * 64;
  const float* invs = (const float*)(wsb + OFFB_INVS) + b * 256;
  const f16* w1h = (const f16*)(wsb + OFFB_W1H);
  const f16* w2h = (const f16*)(wsb + OFFB_W2H);
  const f16* w3h = (const f16*)(wsb + OFFB_W3H);
  const f16* w4h = (const f16*)(wsb + OFFB_W4H);
  const f16* w5h = (const f16*)(wsb + OFFB_W5H);

  __shared__ __align__(16) char yl[65536];   // y1 dbuf [0,32K) | y2 dbuf [32K,64K)
  __shared__ __align__(16) f16 c1h[64 * 264];
  __shared__ __align__(16) float sml[64 * 32];
#define Y1BUF(i) (yl + (i) * 16384)
#define Y2BUF(i) (yl + 32768 + (i) * 16384)

  // ---- stage raw t (64n x 256f, frag order) into yl[0..32K)
  {
    int n = tid & 63, fb = tid >> 6;
#pragma unroll
    for (int j = 0; j < 2; ++j) {
      int foct = j * 16 + fb;
      f16x8 h;
#pragma unroll
      for (int e = 0; e < 8; ++e)
        h[e] = (f16)tf[((size_t)b * FF + foct * 8 + e) * N1 + n];
      *(f16x8*)(yl + ((foct >> 2) * 4 + (n >> 4)) * 1024 +
                ((foct & 3) * 16 + (n & 15)) * 16) = h;
    }
  }
  // ---- stage s_norm (32m x 256f, frag order) into y2 buf0
  {
    int m = tid & 31, foct = tid >> 5;
    float iv = invs[mb + m];
    f16x8 h;
#pragma unroll
    for (int e = 0; e < 8; ++e)
      h[e] = (f16)(sf[((size_t)b * FF + foct * 8 + e) * N2 + mb + m] * iv);
    *(f16x8*)(yl + 32768 + ((foct >> 2) * 2 + (m >> 4)) * 1024 +
              ((foct & 3) * 16 + (m & 15)) * 16) = h;
  }
  __syncthreads();

  // ---- sim-GEMM (waves 0-7): D[n16][m16] = t^T s_norm, scale by invt -> sml
  if (w < 8) {
    const int nt = w >> 1, mfs = w & 1;
    f32x4 sa = {0.f, 0.f, 0.f, 0.f};
#pragma unroll
    for (int ks = 0; ks < 8; ++ks) {
      f16x8 af = *(const f16x8*)(yl + (ks * 4 + nt) * 1024 + lane * 16);
      f16x8 bfm = *(const f16x8*)(yl + 32768 + (ks * 2 + mfs) * 1024 + lane * 16);
      sa = __builtin_amdgcn_mfma_f32_16x16x32_f16(af, bfm, sa, 0, 0, 0);
    }
#pragma unroll
    for (int j = 0; j < 4; ++j) {
      int n = nt * 16 + g * 4 + j;
      sml[n * 32 + mfs * 16 + r] = sa[j] * invt[n];
    }
  }
  // ---- c1-GEMM (all 16 waves, o-split 16): c1[n][o] -> c1h f16
  {
    f16x8 w1f[8];
#pragma unroll
    for (int ks = 0; ks < 8; ++ks)
      w1f[ks] = *(const f16x8*)(w1h + (w * 16 + r) * 256 + ks * 32 + g * 8);
    f32x4 ac[4];
#pragma unroll
    for (int nf = 0; nf < 4; ++nf) ac[nf] = (f32x4){0.f, 0.f, 0.f, 0.f};
#pragma unroll
    for (int ks = 0; ks < 8; ++ks)
#pragma unroll
      for (int nf = 0; nf < 4; ++nf) {
        f16x8 bfm = *(const f16x8*)(yl + (ks * 4 + nf) * 1024 + lane * 16);
        ac[nf] = __builtin_amdgcn_mfma_f32_16x16x32_f16(w1f[ks], bfm, ac[nf], 0, 0, 0);
      }
    f32x4 b1v = *(const f32x4*)(b1 + w * 16 + g * 4);
    f32x4 wx = *(const f32x4*)(w14t + 256 + w * 16 + g * 4);
    f32x4 wy = *(const f32x4*)(w14t + 512 + w * 16 + g * 4);
    f32x4 wz = *(const f32x4*)(w14t + 768 + w * 16 + g * 4);
#pragma unroll
    for (int nf = 0; nf < 4; ++nf) {
      int n = nf * 16 + r;
      const float* sd = seeds + ((size_t)b * 64 + n) * 3;
      float sx = sd[0], sy = sd[1], sz = sd[2];
      f16x4 hv;
#pragma unroll
      for (int j = 0; j < 4; ++j)
        hv[j] = (f16)(ac[nf][j] + b1v[j] + wx[j] * sx + wy[j] * sy + wz[j] * sz);
      *(f16x4*)(c1h + n * 264 + w * 16 + g * 4) = hv;
    }
  }
  __syncthreads();   // sml, c1h published; all t/s reads done

  // ---- persistent registers (same names both groups)
  f16x8 wreg[2][8];
  f32x4 biasv[2];
  f16x4 pool[2][2];
  f32x4 acc[2][2];
  f32x4 w1a, w1b;
  {
    const f16* wsrc = grp ? w3h : w2h;
    const float* bsrc = grp ? b3 : b2;
#pragma unroll
    for (int of = 0; of < 2; ++of) {
#pragma unroll
      for (int ks = 0; ks < 8; ++ks)
        wreg[of][ks] = *(const f16x8*)(wsrc + (wg * 32 + of * 16 + r) * 256 +
                                       ks * 32 + g * 8);
      biasv[of] = *(const f32x4*)(bsrc + wg * 32 + of * 16 + g * 4);
    }
    w1a = *(const f32x4*)(w14t + kp * 32 + g * 8);
    w1b = *(const f32x4*)(w14t + kp * 32 + g * 8 + 4);
  }
#pragma unroll
  for (int of = 0; of < 2; ++of)
#pragma unroll
    for (int mf = 0; mf < 2; ++mf) pool[of][mf] = (f16x4){0, 0, 0, 0};

  PRODUCE_Y1(0, Y1BUF(0));   // overwrites t frags 0-15 (reads done)
  __syncthreads();

  // ---- main loop (1 barrier/iter):
  //   A: GEMM L2(y1[n]) -> produce y1[n+1] frag -> store y2[n]
  //   B: produce y1[n+1] frag -> GEMM L3(y2[n-1]) -> pool
  for (int n = 0; n < N1; ++n) {
    if (grp == 0) {
      ZERO_ACC;
      GEMM2(Y1BUF(n & 1));
      if (n + 1 < N1) PRODUCE_Y1(n + 1, Y1BUF((n + 1) & 1));
      STORE_FRAG(Y2BUF(n & 1));
    } else {
      if (n + 1 < N1) PRODUCE_Y1(n + 1, Y1BUF((n + 1) & 1));
      if (n > 0) {
        ZERO_ACC;
        GEMM2(Y2BUF((n - 1) & 1));
        POOLUP;
      }
    }
    __syncthreads();
  }

  // ---- tail: B finishes L3(63) + writes pooled tile; A loads W4
  if (grp == 1) {
    ZERO_ACC;
    GEMM2(Y2BUF(1));
    POOLUP;
#pragma unroll
    for (int of = 0; of < 2; ++of)
#pragma unroll
      for (int mf = 0; mf < 2; ++mf)
        *(f16x4*)(Y1BUF(0) + (wg * 2 + mf) * 1024 + (of * 2 + (g >> 1)) * 256 +
                  r * 16 + (g & 1) * 8) = pool[of][mf];
  } else {
#pragma unroll
    for (int of = 0; of < 2; ++of) {
#pragma unroll
      for (int ks = 0; ks < 8; ++ks)
        wreg[of][ks] = *(const f16x8*)(w4h + (wg * 32 + of * 16 + r) * 256 +
                                       ks * 32 + g * 8);
      biasv[of] = *(const f32x4*)(b4 + wg * 32 + of * 16 + g * 4);
    }
  }
  __syncthreads();
  // ---- L4 (A); B loads W5
  if (grp == 0) {
    ZERO_ACC;
    GEMM2(Y1BUF(0));
    STORE_FRAG(Y2BUF(0));
  } else {
#pragma unroll
    for (int of = 0; of < 2; ++of) {
#pragma unroll
      for (int ks = 0; ks < 8; ++ks)
        wreg[of][ks] = *(const f16x8*)(w5h + (wg * 32 + of * 16 + r) * 256 +
                                       ks * 32 + g * 8);
      biasv[of] = *(const f32x4*)(b5 + wg * 32 + of * 16 + g * 4);
    }
  }
  __syncthreads();
  // ---- L5 (B, no relu) -> out
  if (grp == 1) {
    ZERO_ACC;
    GEMM2(Y2BUF(0));
#pragma unroll
    for (int of = 0; of < 2; ++of)
#pragma unroll
      for (int mf = 0; mf < 2; ++mf) {
        float* op = out + ((size_t)(b * 256 + wg * 32 + of * 16 + g * 4)) * 256 +
                    mb + mf * 16 + r;
#pragma unroll
        for (int j = 0; j < 4; ++j)
          op[(size_t)j * 256] = acc[of][mf][j] + biasv[of][j];
      }
  }
}

extern "C" void kernel_launch(void* const* d_in, const int* in_sizes, int n_in,
                              void* d_out, int out_size, void* d_ws, size_t ws_size,
                              hipStream_t stream) {
  const float* sf = (const float*)d_in[0];
  const float* tf = (const float*)d_in[1];
  const float* seeds = (const float*)d_in[2];
  const float* W1 = (const float*)d_in[3];
  const float* b1 = (const float*)d_in[4];
  const float* W2 = (const float*)d_in[5];
  const float* b2 = (const float*)d_in[6];
  const float* W3 = (const float*)d_in[7];
  const float* b3 = (const float*)d_in[8];
  const float* W4 = (const float*)d_in[9];
  const float* b4 = (const float*)d_in[10];
  const float* W5 = (const float*)d_in[11];
  const float* b5 = (const float*)d_in[12];
  char* wsb = (char*)d_ws;
  float* out = (float*)d_out;

  k_prep<<<dim3(256, 6), 256, 0, stream>>>(W1, W2, W3, W4, W5, wsb);
  k_norms<<<dim3(BB), 256, 0, stream>>>(sf, tf, wsb);
  k_mega<<<dim3(8, BB), 1024, 0, stream>>>(sf, tf, seeds, b1, b2, b3, b4, b5,
                                           wsb, out);
}

// Round 7
// 135.991 us; speedup vs baseline: 1.2585x; 1.2585x over previous
//
#include <hip/hip_runtime.h>
#include <math.h>

#define BB 32
#define FF 256
#define N1 64
#define N2 256

typedef _Float16 f16;
typedef _Float16 f16x4 __attribute__((ext_vector_type(4)));
typedef _Float16 f16x8 __attribute__((ext_vector_type(8)));
typedef float f32x4 __attribute__((ext_vector_type(4)));

// ---- ws byte offsets ----
#define OFFB_W14T 0u        // 4*256 f32  (W1 cols 0..3, [c][o])
#define OFFB_W1H  45056u    // 256*256 f16 (W1 cols 4..259, [o][k])
#define OFFB_W2H  176128u
#define OFFB_W3H  307200u
#define OFFB_W4H  438272u
#define OFFB_W5H  569344u

__global__ void k_prep(const float* __restrict__ W1, const float* __restrict__ W2,
                       const float* __restrict__ W3, const float* __restrict__ W4,
                       const float* __restrict__ W5, char* __restrict__ wsb) {
  int x = blockIdx.x, m = blockIdx.y, t = threadIdx.x;
  int idx = x * 256 + t;
  if (m == 0)      ((f16*)(wsb + OFFB_W2H))[idx] = (f16)W2[idx];
  else if (m == 1) ((f16*)(wsb + OFFB_W3H))[idx] = (f16)W3[idx];
  else if (m == 2) ((f16*)(wsb + OFFB_W4H))[idx] = (f16)W4[idx];
  else if (m == 3) ((f16*)(wsb + OFFB_W5H))[idx] = (f16)W5[idx];
  else if (m == 4) ((f16*)(wsb + OFFB_W1H))[idx] = (f16)W1[x * 260 + 4 + t];
  else if (x < 4)  ((float*)(wsb + OFFB_W14T))[x * 256 + t] = W1[t * 260 + x];
}

// Fragment-ordered layouts (verified R3-R6):
// 32m x 256k tile: frag(ks,mf) at (ks*2+mf)*1024, lane L at +L*16 (b128, no-conflict)
// 64n x 256f t-tile: frag((f>>5)*4 + (n>>4))*1024.

#define LD(S, KS, MF) (*(const f16x8*)((S) + ((KS) * 2 + (MF)) * 1024 + lane * 16))

#define ZERO_ACC                                                  \
  _Pragma("unroll") for (int of = 0; of < 4; ++of)                \
  _Pragma("unroll") for (int mf = 0; mf < 2; ++mf)                \
      acc[of][mf] = (f32x4){0.f, 0.f, 0.f, 0.f};

// o-range 64 GEMM, prefetch 2 ks-pairs ahead. 32 MFMA, 16 b128 reads.
#define GEMM4(SRC)                                                                \
  {                                                                               \
    f16x8 a0 = LD(SRC, 0, 0), a1 = LD(SRC, 0, 1);                                 \
    f16x8 p0 = LD(SRC, 1, 0), p1 = LD(SRC, 1, 1);                                 \
    __builtin_amdgcn_s_setprio(1);                                                \
    _Pragma("unroll") for (int ks = 0; ks < 8; ++ks) {                            \
      f16x8 c0 = a0, c1 = a1;                                                     \
      a0 = p0; a1 = p1;                                                           \
      if (ks < 6) { p0 = LD(SRC, ks + 2, 0); p1 = LD(SRC, ks + 2, 1); }           \
      _Pragma("unroll") for (int of = 0; of < 4; ++of) {                          \
        acc[of][0] = __builtin_amdgcn_mfma_f32_16x16x32_f16(wreg[of][ks], c0,     \
                                                            acc[of][0], 0, 0, 0); \
        acc[of][1] = __builtin_amdgcn_mfma_f32_16x16x32_f16(wreg[of][ks], c1,     \
                                                            acc[of][1], 0, 0, 0); \
      }                                                                           \
    }                                                                             \
    __builtin_amdgcn_s_setprio(0);                                                \
  }

// bias+relu+cvt, store acc frags into 32m x 256k tile (k = this layer's o, o64)
#define STORE_FRAG(DST)                                                           \
  _Pragma("unroll") for (int of = 0; of < 4; ++of)                                \
  _Pragma("unroll") for (int mf = 0; mf < 2; ++mf) {                              \
    f16x4 hv;                                                                     \
    _Pragma("unroll") for (int j = 0; j < 4; ++j)                                 \
        hv[j] = (f16)fmaxf(acc[of][mf][j] + biasv[of][j], 0.f);                   \
    *(f16x4*)((DST) + ((wg * 2 + (of >> 1)) * 2 + mf) * 1024 +                    \
              ((of & 1) * 2 + (g >> 1)) * 256 + r * 16 + (g & 1) * 8) = hv;       \
  }

#define POOLUP                                                                    \
  _Pragma("unroll") for (int of = 0; of < 4; ++of)                                \
  _Pragma("unroll") for (int mf = 0; mf < 2; ++mf)                                \
  _Pragma("unroll") for (int j = 0; j < 4; ++j) {                                 \
    f16 hv = (f16)fmaxf(acc[of][mf][j] + biasv[of][j], 0.f);                      \
    if (hv > pool[of][mf][j]) pool[of][mf][j] = hv;                               \
  }

// wave w produces y1 frags (ks=w, mf=0/1) for row NN: 1 c1 read serves both.
#define PRODUCE_Y1(NN, DST)                                                       \
  {                                                                               \
    float sv0 = sml[(NN) * 32 + r];                                               \
    float sv1 = sml[(NN) * 32 + 16 + r];                                          \
    f16x8 c8 = *(const f16x8*)(c1h + (NN) * 264 + w * 32 + g * 8);                \
    f16x8 h0, h1;                                                                 \
    _Pragma("unroll") for (int q = 0; q < 4; ++q) {                               \
      float ca = (float)c8[q], cb = (float)c8[4 + q];                             \
      h0[q] = (f16)fmaxf(fmaf(w1a[q], sv0, ca), 0.f);                             \
      h0[4 + q] = (f16)fmaxf(fmaf(w1b[q], sv0, cb), 0.f);                         \
      h1[q] = (f16)fmaxf(fmaf(w1a[q], sv1, ca), 0.f);                             \
      h1[4 + q] = (f16)fmaxf(fmaf(w1b[q], sv1, cb), 0.f);                         \
    }                                                                             \
    *(f16x8*)((DST) + (w * 2) * 1024 + lane * 16) = h0;                           \
    *(f16x8*)((DST) + (w * 2 + 1) * 1024 + lane * 16) = h1;                       \
  }

// 8 waves: A=0-3 (L2/L4), B=4-7 (L3+pool/L5). o-range 64/wave (wreg 128 VGPR).
__global__ __launch_bounds__(512, 2) void k_mega(
    const float* __restrict__ sf, const float* __restrict__ tf,
    const float* __restrict__ seeds, const float* __restrict__ b1,
    const float* __restrict__ b2, const float* __restrict__ b3,
    const float* __restrict__ b4, const float* __restrict__ b5,
    const char* __restrict__ wsb, float* __restrict__ out) {
  const int mt = blockIdx.x, b = blockIdx.y, mb = mt * 32;
  const int tid = threadIdx.x;
  const int w = tid >> 6, lane = tid & 63, g = lane >> 4, r = lane & 15;
  const int grp = w >> 2, wg = w & 3;

  const float* w14t = (const float*)(wsb + OFFB_W14T);
  const f16* w1h = (const f16*)(wsb + OFFB_W1H);
  const f16* w2h = (const f16*)(wsb + OFFB_W2H);
  const f16* w3h = (const f16*)(wsb + OFFB_W3H);
  const f16* w4h = (const f16*)(wsb + OFFB_W4H);
  const f16* w5h = (const f16*)(wsb + OFFB_W5H);

  __shared__ __align__(16) char yl[65536];   // y1 dbuf [0,32K) | y2 dbuf [32K,64K)
  __shared__ __align__(16) f16 c1h[64 * 264];
  __shared__ __align__(16) float sml[64 * 32];
  __shared__ __align__(16) float part_t[64 * 8];
  __shared__ __align__(16) float part_s[32 * 16];
  __shared__ float invt_l[64];
  __shared__ float invs_l[32];
#define Y1BUF(i) (yl + (i) * 16384)
#define Y2BUF(i) (yl + 32768 + (i) * 16384)

  // ---- load t-tile (f32) to regs: wave w owns octs {w, w+8, w+16, w+24}
  float tv[32];
  {
    const int n = lane;
    float ssq = 0.f;
#pragma unroll
    for (int j = 0; j < 4; ++j) {
      int oct = j * 8 + w;
#pragma unroll
      for (int e = 0; e < 8; ++e) {
        float v = tf[((size_t)b * FF + oct * 8 + e) * N1 + n];
        tv[j * 8 + e] = v;
        ssq = fmaf(v, v, ssq);
      }
    }
    part_t[n * 8 + w] = ssq;
  }
  // ---- load s-tile (f32) to regs: thread (m=tid&31, q=tid>>5) octs {q, q+16}
  float sv2[16];
  {
    const int m = tid & 31, q = tid >> 5;
    float ssq = 0.f;
#pragma unroll
    for (int j = 0; j < 2; ++j) {
      int oct = j * 16 + q;
#pragma unroll
      for (int e = 0; e < 8; ++e) {
        float v = sf[((size_t)b * FF + oct * 8 + e) * N2 + mb + m];
        sv2[j * 8 + e] = v;
        ssq = fmaf(v, v, ssq);
      }
    }
    part_s[m * 16 + q] = ssq;
  }
  __syncthreads();
  if (tid < 64) {
    float a = 0.f;
#pragma unroll
    for (int i = 0; i < 8; ++i) a += part_t[tid * 8 + i];
    invt_l[tid] = 1.0f / fmaxf(sqrtf(a), 1e-8f);
  }
  if (tid < 32) {
    float a = 0.f;
#pragma unroll
    for (int i = 0; i < 16; ++i) a += part_s[tid * 16 + i];
    invs_l[tid] = 1.0f / fmaxf(sqrtf(a), 1e-8f);
  }
  __syncthreads();
  // ---- store t frags (raw f16) into yl[0..32K)
  {
    const int n = lane;
#pragma unroll
    for (int j = 0; j < 4; ++j) {
      int oct = j * 8 + w;
      f16x8 h;
#pragma unroll
      for (int e = 0; e < 8; ++e) h[e] = (f16)tv[j * 8 + e];
      *(f16x8*)(yl + ((oct >> 2) * 4 + (n >> 4)) * 1024 +
                ((oct & 3) * 16 + (n & 15)) * 16) = h;
    }
  }
  // ---- store s_norm frags into y2 buf0
  {
    const int m = tid & 31, q = tid >> 5;
    float iv = invs_l[m];
#pragma unroll
    for (int j = 0; j < 2; ++j) {
      int oct = j * 16 + q;
      f16x8 h;
#pragma unroll
      for (int e = 0; e < 8; ++e) h[e] = (f16)(sv2[j * 8 + e] * iv);
      *(f16x8*)(yl + 32768 + ((oct >> 2) * 2 + (m >> 4)) * 1024 +
                ((oct & 3) * 16 + (m & 15)) * 16) = h;
    }
  }
  __syncthreads();

  // ---- sim-GEMM (all 8 waves, frag (nt=w>>1, mfs=w&1)): scale by invt -> sml
  {
    const int nt = w >> 1, mfs = w & 1;
    f32x4 sa = {0.f, 0.f, 0.f, 0.f};
#pragma unroll
    for (int ks = 0; ks < 8; ++ks) {
      f16x8 af = *(const f16x8*)(yl + (ks * 4 + nt) * 1024 + lane * 16);
      f16x8 bfm = *(const f16x8*)(yl + 32768 + (ks * 2 + mfs) * 1024 + lane * 16);
      sa = __builtin_amdgcn_mfma_f32_16x16x32_f16(af, bfm, sa, 0, 0, 0);
    }
#pragma unroll
    for (int j = 0; j < 4; ++j) {
      int n = nt * 16 + g * 4 + j;
      sml[n * 32 + mfs * 16 + r] = sa[j] * invt_l[n];
    }
  }
  // ---- c1-GEMM (8 waves, o-split 32): c1[n][o] -> c1h f16
  {
    f16x8 w1f[2][8];
#pragma unroll
    for (int ofl = 0; ofl < 2; ++ofl)
#pragma unroll
      for (int ks = 0; ks < 8; ++ks)
        w1f[ofl][ks] = *(const f16x8*)(w1h + (w * 32 + ofl * 16 + r) * 256 +
                                       ks * 32 + g * 8);
    f32x4 ac[2][4];
#pragma unroll
    for (int ofl = 0; ofl < 2; ++ofl)
#pragma unroll
      for (int nf = 0; nf < 4; ++nf) ac[ofl][nf] = (f32x4){0.f, 0.f, 0.f, 0.f};
#pragma unroll
    for (int ks = 0; ks < 8; ++ks)
#pragma unroll
      for (int nf = 0; nf < 4; ++nf) {
        f16x8 bfm = *(const f16x8*)(yl + (ks * 4 + nf) * 1024 + lane * 16);
        ac[0][nf] = __builtin_amdgcn_mfma_f32_16x16x32_f16(w1f[0][ks], bfm,
                                                           ac[0][nf], 0, 0, 0);
        ac[1][nf] = __builtin_amdgcn_mfma_f32_16x16x32_f16(w1f[1][ks], bfm,
                                                           ac[1][nf], 0, 0, 0);
      }
    f32x4 b1v[2], wx[2], wy[2], wz[2];
#pragma unroll
    for (int ofl = 0; ofl < 2; ++ofl) {
      int o = w * 32 + ofl * 16 + g * 4;
      b1v[ofl] = *(const f32x4*)(b1 + o);
      wx[ofl] = *(const f32x4*)(w14t + 256 + o);
      wy[ofl] = *(const f32x4*)(w14t + 512 + o);
      wz[ofl] = *(const f32x4*)(w14t + 768 + o);
    }
#pragma unroll
    for (int nf = 0; nf < 4; ++nf) {
      int n = nf * 16 + r;
      const float* sd = seeds + ((size_t)b * 64 + n) * 3;
      float sx = sd[0], sy = sd[1], sz = sd[2];
#pragma unroll
      for (int ofl = 0; ofl < 2; ++ofl) {
        f16x4 hv;
#pragma unroll
        for (int j = 0; j < 4; ++j)
          hv[j] = (f16)(ac[ofl][nf][j] + b1v[ofl][j] + wx[ofl][j] * sx +
                        wy[ofl][j] * sy + wz[ofl][j] * sz);
        *(f16x4*)(c1h + n * 264 + w * 32 + ofl * 16 + g * 4) = hv;
      }
    }
  }
  __syncthreads();   // sml, c1h published; all t/s reads done

  // ---- persistent registers (same names both groups)
  f16x8 wreg[4][8];
  f32x4 biasv[4];
  f16x4 pool[4][2];
  f32x4 acc[4][2];
  f32x4 w1a, w1b;
  {
    const f16* wsrc = grp ? w3h : w2h;
    const float* bsrc = grp ? b3 : b2;
#pragma unroll
    for (int of = 0; of < 4; ++of) {
#pragma unroll
      for (int ks = 0; ks < 8; ++ks)
        wreg[of][ks] = *(const f16x8*)(wsrc + (wg * 64 + of * 16 + r) * 256 +
                                       ks * 32 + g * 8);
      biasv[of] = *(const f32x4*)(bsrc + wg * 64 + of * 16 + g * 4);
    }
    w1a = *(const f32x4*)(w14t + w * 32 + g * 8);
    w1b = *(const f32x4*)(w14t + w * 32 + g * 8 + 4);
  }
#pragma unroll
  for (int of = 0; of < 4; ++of)
#pragma unroll
    for (int mf = 0; mf < 2; ++mf) pool[of][mf] = (f16x4){0, 0, 0, 0};

  PRODUCE_Y1(0, Y1BUF(0));   // overwrites t frags (reads done)
  __syncthreads();

  // ---- main loop (1 barrier/iter):
  //   A: GEMM L2(y1[n]) -> produce y1[n+1] -> store y2[n]
  //   B: produce y1[n+1] -> GEMM L3(y2[n-1]) -> pool
  for (int n = 0; n < N1; ++n) {
    if (grp == 0) {
      ZERO_ACC;
      GEMM4(Y1BUF(n & 1));
      if (n + 1 < N1) PRODUCE_Y1(n + 1, Y1BUF((n + 1) & 1));
      STORE_FRAG(Y2BUF(n & 1));
    } else {
      if (n + 1 < N1) PRODUCE_Y1(n + 1, Y1BUF((n + 1) & 1));
      if (n > 0) {
        ZERO_ACC;
        GEMM4(Y2BUF((n - 1) & 1));
        POOLUP;
      }
    }
    __syncthreads();
  }

  // ---- tail: B finishes L3(63) + writes pooled tile; A loads W4
  if (grp == 1) {
    ZERO_ACC;
    GEMM4(Y2BUF(1));
    POOLUP;
#pragma unroll
    for (int of = 0; of < 4; ++of)
#pragma unroll
      for (int mf = 0; mf < 2; ++mf)
        *(f16x4*)(Y1BUF(0) + ((wg * 2 + (of >> 1)) * 2 + mf) * 1024 +
                  ((of & 1) * 2 + (g >> 1)) * 256 + r * 16 + (g & 1) * 8) =
            pool[of][mf];
  } else {
#pragma unroll
    for (int of = 0; of < 4; ++of) {
#pragma unroll
      for (int ks = 0; ks < 8; ++ks)
        wreg[of][ks] = *(const f16x8*)(w4h + (wg * 64 + of * 16 + r) * 256 +
                                       ks * 32 + g * 8);
      biasv[of] = *(const f32x4*)(b4 + wg * 64 + of * 16 + g * 4);
    }
  }
  __syncthreads();
  // ---- L4 (A); B loads W5
  if (grp == 0) {
    ZERO_ACC;
    GEMM4(Y1BUF(0));
    STORE_FRAG(Y2BUF(0));
  } else {
#pragma unroll
    for (int of = 0; of < 4; ++of) {
#pragma unroll
      for (int ks = 0; ks < 8; ++ks)
        wreg[of][ks] = *(const f16x8*)(w5h + (wg * 64 + of * 16 + r) * 256 +
                                       ks * 32 + g * 8);
      biasv[of] = *(const f32x4*)(b5 + wg * 64 + of * 16 + g * 4);
    }
  }
  __syncthreads();
  // ---- L5 (B, no relu) -> out
  if (grp == 1) {
    ZERO_ACC;
    GEMM4(Y2BUF(0));
#pragma unroll
    for (int of = 0; of < 4; ++of)
#pragma unroll
      for (int mf = 0; mf < 2; ++mf) {
        float* op = out + ((size_t)(b * 256 + wg * 64 + of * 16 + g * 4)) * 256 +
                    mb + mf * 16 + r;
#pragma unroll
        for (int j = 0; j < 4; ++j)
          op[(size_t)j * 256] = acc[of][mf][j] + biasv[of][j];
      }
  }
}

extern "C" void kernel_launch(void* const* d_in, const int* in_sizes, int n_in,
                              void* d_out, int out_size, void* d_ws, size_t ws_size,
                              hipStream_t stream) {
  const float* sf = (const float*)d_in[0];
  const float* tf = (const float*)d_in[1];
  const float* seeds = (const float*)d_in[2];
  const float* W1 = (const float*)d_in[3];
  const float* b1 = (const float*)d_in[4];
  const float* W2 = (const float*)d_in[5];
  const float* b2 = (const float*)d_in[6];
  const float* W3 = (const float*)d_in[7];
  const float* b3 = (const float*)d_in[8];
  const float* W4 = (const float*)d_in[9];
  const float* b4 = (const float*)d_in[10];
  const float* W5 = (const float*)d_in[11];
  const float* b5 = (const float*)d_in[12];
  char* wsb = (char*)d_ws;
  float* out = (float*)d_out;

  k_prep<<<dim3(256, 6), 256, 0, stream>>>(W1, W2, W3, W4, W5, wsb);
  k_mega<<<dim3(8, BB), 512, 0, stream>>>(sf, tf, seeds, b1, b2, b3, b4, b5,
                                          wsb, out);
}